// Round 1
// baseline (658.794 us; speedup 1.0000x reference)
//
#include <hip/hip_runtime.h>
#include <math.h>

// Problem constants (from reference setup_inputs)
#define B_  8
#define C_  64      // Cin
#define O_  64      // Cout
#define H_  128
#define W_  128
#define KK_ 9
#define HW_ (H_ * W_)

// Fused kernel: one thread per output pixel (b, ho, wo).
// Phase 1: 27-channel 3x3 conv (18 offsets + 9 modulators) into registers.
// Phase 2: 9-tap modulated bilinear gather + 64-output-channel contraction.
__global__ __launch_bounds__(256) void dcn_fused_kernel(
    const float* __restrict__ x,      // (B, C, H, W)
    const float* __restrict__ offw,   // (18, C, 3, 3)
    const float* __restrict__ offb,   // (18,)
    const float* __restrict__ modw,   // (9, C, 3, 3)
    const float* __restrict__ modb,   // (9,)
    const float* __restrict__ wgt,    // (O, C, 3, 3)
    float* __restrict__ out)          // (B, O, H, W)
{
    const int wo = threadIdx.x;                       // 0..127
    const int ho = blockIdx.x * blockDim.y + threadIdx.y;
    const int b  = blockIdx.y;

    const float* __restrict__ xb = x + (size_t)b * C_ * HW_;

    // ---------------- Phase 1: offset/modulator conv ----------------
    float ofs[18];
    float md[9];
#pragma unroll
    for (int t = 0; t < 18; ++t) ofs[t] = offb[t];
#pragma unroll
    for (int t = 0; t < 9; ++t)  md[t]  = modb[t];

    for (int c = 0; c < C_; ++c) {
        const float* __restrict__ xc = xb + c * HW_;
        float p[9];
#pragma unroll
        for (int i = 0; i < 3; ++i) {
            const int y = ho - 1 + i;
            const bool vy = (y >= 0) && (y < H_);
#pragma unroll
            for (int j = 0; j < 3; ++j) {
                const int xx = wo - 1 + j;
                const bool v = vy && (xx >= 0) && (xx < W_);
                p[i * 3 + j] = v ? xc[y * W_ + xx] : 0.0f;
            }
        }
        const float* __restrict__ w1 = offw + c * 9;   // + t*576 + tap
#pragma unroll
        for (int t = 0; t < 18; ++t) {
#pragma unroll
            for (int tap = 0; tap < 9; ++tap)
                ofs[t] = fmaf(p[tap], w1[t * (C_ * 9) + tap], ofs[t]);
        }
        const float* __restrict__ w2 = modw + c * 9;
#pragma unroll
        for (int t = 0; t < 9; ++t) {
#pragma unroll
            for (int tap = 0; tap < 9; ++tap)
                md[t] = fmaf(p[tap], w2[t * (C_ * 9) + tap], md[t]);
        }
    }

    // dy[k] = ofs[2k], dx[k] = ofs[2k+1]; mask = 2*sigmoid(md)
    float dy9[9], dx9[9], mk9[9];
#pragma unroll
    for (int k = 0; k < 9; ++k) {
        dy9[k] = ofs[2 * k];
        dx9[k] = ofs[2 * k + 1];
        mk9[k] = 2.0f / (1.0f + expf(-md[k]));
    }

    // ---------------- Phase 2: deformable gather + contraction ----------------
    float acc[O_];
#pragma unroll
    for (int o = 0; o < O_; ++o) acc[o] = 0.0f;

    for (int k = 0; k < KK_; ++k) {
        const int ki = k / 3, kj = k % 3;
        const float ys = (float)(ho - 1 + ki) + dy9[k];
        const float xs = (float)(wo - 1 + kj) + dx9[k];
        const float y0f = floorf(ys), x0f = floorf(xs);
        const float wy = ys - y0f, wx = xs - x0f;
        const int y0 = (int)y0f, x0 = (int)x0f;
        const int y1 = y0 + 1,  x1 = x0 + 1;

        const bool vy0 = (y0 >= 0) && (y0 < H_);
        const bool vy1 = (y1 >= 0) && (y1 < H_);
        const bool vx0 = (x0 >= 0) && (x0 < W_);
        const bool vx1 = (x1 >= 0) && (x1 < W_);

        const int yc0 = min(max(y0, 0), H_ - 1);
        const int yc1 = min(max(y1, 0), H_ - 1);
        const int xc0 = min(max(x0, 0), W_ - 1);
        const int xc1 = min(max(x1, 0), W_ - 1);

        const float m = mk9[k];
        float w00 = (1.0f - wy) * (1.0f - wx) * m; if (!(vy0 && vx0)) w00 = 0.0f;
        float w01 = (1.0f - wy) * wx          * m; if (!(vy0 && vx1)) w01 = 0.0f;
        float w10 = wy          * (1.0f - wx) * m; if (!(vy1 && vx0)) w10 = 0.0f;
        float w11 = wy          * wx          * m; if (!(vy1 && vx1)) w11 = 0.0f;

        const int i00 = yc0 * W_ + xc0;
        const int i01 = yc0 * W_ + xc1;
        const int i10 = yc1 * W_ + xc0;
        const int i11 = yc1 * W_ + xc1;

        for (int c = 0; c < C_; ++c) {
            const float* __restrict__ xc = xb + c * HW_;
            const float val = w00 * xc[i00] + w01 * xc[i01]
                            + w10 * xc[i10] + w11 * xc[i11];
            const float* __restrict__ wk = wgt + c * 9 + k;  // + o*576
#pragma unroll
            for (int o = 0; o < O_; ++o)
                acc[o] = fmaf(val, wk[o * (C_ * 9)], acc[o]);
        }
    }

    // ---------------- Store ----------------
    float* __restrict__ ob = out + ((size_t)b * O_) * HW_ + ho * W_ + wo;
#pragma unroll
    for (int o = 0; o < O_; ++o)
        ob[o * HW_] = acc[o];
}

extern "C" void kernel_launch(void* const* d_in, const int* in_sizes, int n_in,
                              void* d_out, int out_size, void* d_ws, size_t ws_size,
                              hipStream_t stream) {
    (void)in_sizes; (void)n_in; (void)out_size; (void)d_ws; (void)ws_size;
    const float* x    = (const float*)d_in[0];
    const float* offw = (const float*)d_in[1];
    const float* offb = (const float*)d_in[2];
    const float* modw = (const float*)d_in[3];
    const float* modb = (const float*)d_in[4];
    const float* wgt  = (const float*)d_in[5];
    float* out = (float*)d_out;

    dim3 block(W_, 2);            // 256 threads = 4 waves
    dim3 grid(H_ / 2, B_);        // 64 x 8 = 512 blocks
    dcn_fused_kernel<<<grid, block, 0, stream>>>(x, offw, offb, modw, modb, wgt, out);
}

// Round 2
// 576.813 us; speedup vs baseline: 1.1421x; 1.1421x over previous
//
#include <hip/hip_runtime.h>
#include <math.h>

// Problem constants (from reference setup_inputs)
#define B_   8
#define C_   64      // Cin
#define O_   64      // Cout
#define H_   128
#define W_   128
#define HW_  (H_ * W_)
#define KK_  9
#define KSZ  576     // C_*KK_ total contraction length
#define PSTR 40      // LDS leading-dim stride in bf16 elems (80B: 16B-aligned, 2-way max conflict)

typedef __bf16 bf16x8 __attribute__((ext_vector_type(8)));
typedef float  f32x4  __attribute__((ext_vector_type(4)));

// ---------------------------------------------------------------------------
// Kernel 1: 27-channel 3x3 conv producing (dy, dx, mask) per pixel.
// Block = 256 threads: 128 pixels (one image row) x 2 channel-halves.
// Output layout (in d_ws): params[b][t][Ho*Wo], t = 3k+{0:dy,1:dx,2:mask}.
// ---------------------------------------------------------------------------
__global__ __launch_bounds__(256) void dcn_offsets_kernel(
    const float* __restrict__ x,      // (B, C, H, W)
    const float* __restrict__ offw,   // (18, C, 3, 3)
    const float* __restrict__ offb,   // (18,)
    const float* __restrict__ modw,   // (9, C, 3, 3)
    const float* __restrict__ modb,   // (9,)
    float* __restrict__ params)       // (B, 27, H*W)
{
    __shared__ float red[27 * 128];

    const int tid  = threadIdx.x;
    const int pxl  = tid & 127;          // wo
    const int half = tid >> 7;           // 0/1: channel half
    const int b    = blockIdx.x & 7;     // XCD-pinned batch
    const int ho   = blockIdx.x >> 3;

    const float* __restrict__ xb = x + (size_t)b * C_ * HW_;

    float ofs[18];
    float md[9];
#pragma unroll
    for (int t = 0; t < 18; ++t) ofs[t] = 0.0f;
#pragma unroll
    for (int t = 0; t < 9; ++t)  md[t]  = 0.0f;

    const int c0 = half * 32;
    for (int c = c0; c < c0 + 32; ++c) {
        const float* __restrict__ xc = xb + c * HW_;
        float p[9];
#pragma unroll
        for (int i = 0; i < 3; ++i) {
            const int y = ho - 1 + i;
            const bool vy = (y >= 0) && (y < H_);
#pragma unroll
            for (int j = 0; j < 3; ++j) {
                const int xx = pxl - 1 + j;
                const bool v = vy && (xx >= 0) && (xx < W_);
                p[i * 3 + j] = v ? xc[y * W_ + xx] : 0.0f;
            }
        }
        const float* __restrict__ w1 = offw + c * 9;   // + t*576 + tap (scalar loads)
#pragma unroll
        for (int t = 0; t < 18; ++t)
#pragma unroll
            for (int tap = 0; tap < 9; ++tap)
                ofs[t] = fmaf(p[tap], w1[t * KSZ + tap], ofs[t]);
        const float* __restrict__ w2 = modw + c * 9;
#pragma unroll
        for (int t = 0; t < 9; ++t)
#pragma unroll
            for (int tap = 0; tap < 9; ++tap)
                md[t] = fmaf(p[tap], w2[t * KSZ + tap], md[t]);
    }

    if (half == 1) {
#pragma unroll
        for (int t = 0; t < 18; ++t) red[t * 128 + pxl] = ofs[t];
#pragma unroll
        for (int t = 0; t < 9; ++t)  red[(18 + t) * 128 + pxl] = md[t];
    }
    __syncthreads();
    if (half == 0) {
        float* __restrict__ pp = params + (size_t)b * 27 * HW_ + ho * W_ + pxl;
#pragma unroll
        for (int k = 0; k < 9; ++k) {
            const float dy = ofs[2 * k]     + red[(2 * k) * 128 + pxl]     + offb[2 * k];
            const float dx = ofs[2 * k + 1] + red[(2 * k + 1) * 128 + pxl] + offb[2 * k + 1];
            const float z  = md[k]          + red[(18 + k) * 128 + pxl]    + modb[k];
            const float m  = 2.0f / (1.0f + expf(-z));
            pp[(3 * k)     * HW_] = dy;
            pp[(3 * k + 1) * HW_] = dx;
            pp[(3 * k + 2) * HW_] = m;
        }
    }
}

// ---------------------------------------------------------------------------
// Kernel 2: deformable gather + MFMA contraction.
// Block = 256 threads (4 waves) handles one image row (128 px) of one batch,
// all 64 output channels.  GEMM view: D[64 o][128 px] = W[64][576] * P[576][128],
// contraction index K' = k*64 + c (c fastest) so each 32-chunk has fixed tap k.
// Per K-step: threads gather bilinear samples (bf16) into LDS, stage the W
// chunk (bf16), then each wave does 4x2 mfma_f32_16x16x32_bf16 tiles.
// ---------------------------------------------------------------------------
__global__ __launch_bounds__(256, 4) void dcn_mfma_kernel(
    const float* __restrict__ x,      // (B, C, H, W)
    const float* __restrict__ wgt,    // (O, C, 3, 3) -> [o][c*9+k]
    const float* __restrict__ params, // (B, 27, H*W)
    float* __restrict__ out)          // (B, O, H, W)
{
    __shared__ __align__(16) __bf16 Pl[128 * PSTR];  // patches [px][kk]
    __shared__ __align__(16) __bf16 Wl[64 * PSTR];   // weights [o][kk]

    const int tid  = threadIdx.x;
    const int pxl  = tid & 127;          // wo
    const int h    = tid >> 7;           // 0/1: c-half of the 32-chunk
    const int wave = tid >> 6;
    const int lane = tid & 63;
    const int b    = blockIdx.x & 7;     // XCD-pinned batch
    const int ho   = blockIdx.x >> 3;

    const float* __restrict__ xb = x + (size_t)b * C_ * HW_;
    const float* __restrict__ pb = params + (size_t)b * 27 * HW_ + ho * W_ + pxl;

    // W-staging assignment (fixed across steps)
    const int wo_ = tid >> 2;            // 0..63 output channel
    const int kkb = (tid & 3) * 8;       // kk sub-block

    f32x4 acc[4][2];
#pragma unroll
    for (int mt = 0; mt < 4; ++mt)
#pragma unroll
        for (int nt = 0; nt < 2; ++nt)
            acc[mt][nt] = (f32x4){0.f, 0.f, 0.f, 0.f};

    for (int s = 0; s < 18; ++s) {
        const int k  = s >> 1;               // tap for this chunk
        const int cb = (s & 1) * 32;         // chunk channel base
        const int ki = k / 3, kj = k % 3;

        // ---- producer: bilinear params once per (px, k), reuse over 16 c ----
        const float dy = pb[(3 * k)     * HW_];
        const float dx = pb[(3 * k + 1) * HW_];
        const float mk = pb[(3 * k + 2) * HW_];

        const float ys = (float)(ho - 1 + ki) + dy;
        const float xs = (float)(pxl - 1 + kj) + dx;
        const float y0f = floorf(ys), x0f = floorf(xs);
        const float wy = ys - y0f, wx = xs - x0f;
        const int y0 = (int)y0f, x0 = (int)x0f;
        const int y1 = y0 + 1,  x1 = x0 + 1;
        const bool vy0 = (y0 >= 0) && (y0 < H_);
        const bool vy1 = (y1 >= 0) && (y1 < H_);
        const bool vx0 = (x0 >= 0) && (x0 < W_);
        const bool vx1 = (x1 >= 0) && (x1 < W_);
        const int yc0 = min(max(y0, 0), H_ - 1);
        const int yc1 = min(max(y1, 0), H_ - 1);
        const int xc0 = min(max(x0, 0), W_ - 1);
        const int xc1 = min(max(x1, 0), W_ - 1);
        float w00 = (1.0f - wy) * (1.0f - wx) * mk; if (!(vy0 && vx0)) w00 = 0.0f;
        float w01 = (1.0f - wy) * wx          * mk; if (!(vy0 && vx1)) w01 = 0.0f;
        float w10 = wy          * (1.0f - wx) * mk; if (!(vy1 && vx0)) w10 = 0.0f;
        float w11 = wy          * wx          * mk; if (!(vy1 && vx1)) w11 = 0.0f;

        const int cc0 = cb + h * 16;         // this thread's 16 channels
        const float* __restrict__ p00 = xb + (size_t)cc0 * HW_ + yc0 * W_ + xc0;
        const float* __restrict__ p01 = xb + (size_t)cc0 * HW_ + yc0 * W_ + xc1;
        const float* __restrict__ p10 = xb + (size_t)cc0 * HW_ + yc1 * W_ + xc0;
        const float* __restrict__ p11 = xb + (size_t)cc0 * HW_ + yc1 * W_ + xc1;

        bf16x8 v0, v1;
#pragma unroll
        for (int cc = 0; cc < 8; ++cc) {
            const float val = fmaf(w00, p00[cc * HW_],
                             fmaf(w01, p01[cc * HW_],
                             fmaf(w10, p10[cc * HW_], w11 * p11[cc * HW_])));
            v0[cc] = (__bf16)val;
        }
#pragma unroll
        for (int cc = 8; cc < 16; ++cc) {
            const float val = fmaf(w00, p00[cc * HW_],
                             fmaf(w01, p01[cc * HW_],
                             fmaf(w10, p10[cc * HW_], w11 * p11[cc * HW_])));
            v1[cc - 8] = (__bf16)val;
        }
        *(bf16x8*)&Pl[pxl * PSTR + h * 16]     = v0;
        *(bf16x8*)&Pl[pxl * PSTR + h * 16 + 8] = v1;

        // ---- stage W chunk: element (o, kk) <- wgt[o*576 + (cb+kk)*9 + k] ----
        {
            const float* __restrict__ wp = wgt + (size_t)wo_ * KSZ + (size_t)(cb + kkb) * 9 + k;
            bf16x8 wv;
#pragma unroll
            for (int j = 0; j < 8; ++j) wv[j] = (__bf16)wp[j * 9];
            *(bf16x8*)&Wl[wo_ * PSTR + kkb] = wv;
        }
        __syncthreads();

        // ---- consumer: 4 mt x 2 nt MFMA tiles per wave ----
        const int lq = lane >> 4;            // quad 0..3 -> k sub-block
        const int ln = lane & 15;
        bf16x8 bf[2];
#pragma unroll
        for (int nt = 0; nt < 2; ++nt)
            bf[nt] = *(const bf16x8*)&Pl[(wave * 32 + nt * 16 + ln) * PSTR + lq * 8];
        bf16x8 af[4];
#pragma unroll
        for (int mt = 0; mt < 4; ++mt)
            af[mt] = *(const bf16x8*)&Wl[(mt * 16 + ln) * PSTR + lq * 8];
#pragma unroll
        for (int mt = 0; mt < 4; ++mt)
#pragma unroll
            for (int nt = 0; nt < 2; ++nt)
                acc[mt][nt] = __builtin_amdgcn_mfma_f32_16x16x32_bf16(
                    af[mt], bf[nt], acc[mt][nt], 0, 0, 0);
        __syncthreads();
    }

    // ---- epilogue: D col = lane&15 (px), row = (lane>>4)*4 + r (o) ----
    float* __restrict__ ob = out + (size_t)b * O_ * HW_ + (size_t)ho * W_;
    const int n     = wave * 32 + (lane & 15);
    const int rbase = (lane >> 4) * 4;
#pragma unroll
    for (int mt = 0; mt < 4; ++mt)
#pragma unroll
        for (int nt = 0; nt < 2; ++nt)
#pragma unroll
            for (int r = 0; r < 4; ++r)
                ob[(size_t)(mt * 16 + rbase + r) * HW_ + n + nt * 16] = acc[mt][nt][r];
}

extern "C" void kernel_launch(void* const* d_in, const int* in_sizes, int n_in,
                              void* d_out, int out_size, void* d_ws, size_t ws_size,
                              hipStream_t stream) {
    (void)in_sizes; (void)n_in; (void)out_size; (void)ws_size;
    const float* x    = (const float*)d_in[0];
    const float* offw = (const float*)d_in[1];
    const float* offb = (const float*)d_in[2];
    const float* modw = (const float*)d_in[3];
    const float* modb = (const float*)d_in[4];
    const float* wgt  = (const float*)d_in[5];
    float* out    = (float*)d_out;
    float* params = (float*)d_ws;   // needs B*27*HW*4 = 14.2 MB

    dim3 block(256);
    dim3 grid(B_ * H_);             // 1024 blocks; blockIdx&7 = batch (XCD pin)
    dcn_offsets_kernel<<<grid, block, 0, stream>>>(x, offw, offb, modw, modb, params);
    dcn_mfma_kernel<<<grid, block, 0, stream>>>(x, wgt, params, out);
}

// Round 3
// 301.337 us; speedup vs baseline: 2.1862x; 1.9142x over previous
//
#include <hip/hip_runtime.h>
#include <math.h>

// Problem constants
#define B_   8
#define C_   64
#define O_   64
#define H_   128
#define W_   128
#define HW_  (H_ * W_)
#define KSZ  576            // C_*9 contraction length
#define PSTR 40             // LDS leading-dim stride (bf16 elems); 80 B rows, 16B-aligned

typedef __bf16 bf16x8 __attribute__((ext_vector_type(8)));
typedef float  f32x4  __attribute__((ext_vector_type(4)));

#define WPM_ELEMS (18 * 4 * 64 * 8)   // main-weight frags:   36864 bf16 (73728 B)
#define WPA_ELEMS (18 * 2 * 64 * 8)   // offset-weight frags: 18432 bf16 (36864 B)

// ---------------------------------------------------------------------------
// Prepack: convert weights to bf16 laid out EXACTLY as MFMA A-fragments so the
// main kernel loads them as lane-consecutive 16B from global (no LDS staging).
// Chunk s (0..17): tap k = s>>1, channel base cb = (s&1)*32.
// A-frag element (m-tile mt, lane, j): row = mt*16+(lane&15), kk = (lane>>4)*8+j.
// Main:  row = o (64 rows, 4 m-tiles);  OffA: row = t (27 used of 32, 2 m-tiles),
//        t<18 -> offw[t], 18<=t<27 -> modw[t-18], else 0.
// ---------------------------------------------------------------------------
__global__ __launch_bounds__(256) void prepack_kernel(
    const float* __restrict__ offw, const float* __restrict__ modw,
    const float* __restrict__ wgt,
    __bf16* __restrict__ wpM, __bf16* __restrict__ wpA)
{
    const int g = blockIdx.x * 256 + threadIdx.x;
    if (g < 18 * 4 * 64) {
        const int s = g >> 8, mt = (g >> 6) & 3, lane = g & 63;
        const int k = s >> 1, cb = (s & 1) * 32;
        const int o  = mt * 16 + (lane & 15);
        const int c0 = cb + (lane >> 4) * 8;
        bf16x8 v;
#pragma unroll
        for (int j = 0; j < 8; ++j) v[j] = (__bf16)wgt[o * KSZ + (c0 + j) * 9 + k];
        *(bf16x8*)&wpM[(size_t)g * 8] = v;
    } else if (g < 18 * 4 * 64 + 18 * 2 * 64) {
        const int u = g - 18 * 4 * 64;
        const int s = u >> 7, mt = (u >> 6) & 1, lane = u & 63;
        const int k = s >> 1, cb = (s & 1) * 32;
        const int t  = mt * 16 + (lane & 15);
        const int c0 = cb + (lane >> 4) * 8;
        bf16x8 v;
#pragma unroll
        for (int j = 0; j < 8; ++j) {
            float w = 0.0f;
            if (t < 18)      w = offw[t * KSZ + (c0 + j) * 9 + k];
            else if (t < 27) w = modw[(t - 18) * KSZ + (c0 + j) * 9 + k];
            v[j] = (__bf16)w;
        }
        *(bf16x8*)&wpA[(size_t)u * 8] = v;
    }
}

// ---------------------------------------------------------------------------
// Fused kernel. Block = 256 thr (4 waves) owns 64 px (half a row) of one batch.
// Phase A: im2col MFMA -> 27 params/px into LDS (bias + 2*sigmoid applied).
// Phase B: deformable bilinear gather (8 ch/thread) -> LDS -> MFMA, 64 Cout.
// Contraction order K' = tap*64 + c; chunk s has fixed tap -> bilinear params
// computed once per (px, tap) and reused over channels.
// ---------------------------------------------------------------------------
__global__ __launch_bounds__(256) void dcn_main_kernel(
    const float* __restrict__ x,      // (B, C, H, W)
    const __bf16* __restrict__ wpA,   // packed offset/mod weight frags
    const __bf16* __restrict__ wpM,   // packed main weight frags
    const float* __restrict__ offb,   // (18,)
    const float* __restrict__ modb,   // (9,)
    float* __restrict__ out)          // (B, O, H, W)
{
    __shared__ __align__(16) __bf16 Pl[64 * PSTR];   // patches [px][32 kk]
    __shared__ float params[27 * 65];                // [t][px], pad 65 vs bank conflicts

    const int tid  = threadIdx.x;
    const int px   = tid & 63;           // local pixel
    const int h    = tid >> 6;           // 8-channel group (== wave id)
    const int lane = tid & 63;
    const int wave = tid >> 6;
    const int lq   = lane >> 4;          // quad
    const int ln   = lane & 15;

    const int bi   = blockIdx.x;
    const int b    = bi & 7;             // XCD-pinned batch
    const int rest = bi >> 3;
    const int ho   = rest >> 1;
    const int xh   = rest & 1;
    const int wo   = xh * 64 + px;

    const float* __restrict__ xb = x + (size_t)b * C_ * HW_;

    // ---------------- Phase A: offset/modulator conv via MFMA ----------------
    f32x4 accA[2];
    accA[0] = (f32x4){0.f, 0.f, 0.f, 0.f};
    accA[1] = (f32x4){0.f, 0.f, 0.f, 0.f};

    for (int s = 0; s < 18; ++s) {
        const int k = s >> 1, cb = (s & 1) * 32;
        const int ki = k / 3, kj = k - ki * 3;
        const int y  = ho - 1 + ki;
        const int xx = wo - 1 + kj;
        const bool v = (y >= 0) && (y < H_) && (xx >= 0) && (xx < W_);
        const float* __restrict__ xp = xb + (size_t)(cb + h * 8) * HW_ + y * W_ + xx;
        bf16x8 pv;
        if (v) {
#pragma unroll
            for (int j = 0; j < 8; ++j) pv[j] = (__bf16)xp[(size_t)j * HW_];
        } else {
#pragma unroll
            for (int j = 0; j < 8; ++j) pv[j] = (__bf16)0.0f;
        }
        bf16x8 afA[2];
#pragma unroll
        for (int mt = 0; mt < 2; ++mt)
            afA[mt] = *(const bf16x8*)&wpA[(size_t)((s * 2 + mt) * 64 + lane) * 8];

        *(bf16x8*)&Pl[px * PSTR + h * 8] = pv;
        __syncthreads();
        const bf16x8 bfA = *(const bf16x8*)&Pl[(wave * 16 + ln) * PSTR + lq * 8];
#pragma unroll
        for (int mt = 0; mt < 2; ++mt)
            accA[mt] = __builtin_amdgcn_mfma_f32_16x16x32_bf16(afA[mt], bfA, accA[mt], 0, 0, 0);
        __syncthreads();
    }

    // Epilogue A: C/D layout col = lane&15 (px), row = quad*4 + r (param t).
#pragma unroll
    for (int mt = 0; mt < 2; ++mt)
#pragma unroll
        for (int r = 0; r < 4; ++r) {
            const int t   = mt * 16 + lq * 4 + r;
            const int pxl = wave * 16 + ln;
            const float val = accA[mt][r];
            if (t < 18)      params[t * 65 + pxl] = val + offb[t];
            else if (t < 27) params[t * 65 + pxl] = 2.0f / (1.0f + expf(-(val + modb[t - 18])));
        }
    __syncthreads();

    // ---------------- Phase B: deformable gather + MFMA ----------------
    f32x4 acc[4];
#pragma unroll
    for (int mt = 0; mt < 4; ++mt) acc[mt] = (f32x4){0.f, 0.f, 0.f, 0.f};

    for (int s = 0; s < 18; ++s) {
        const int k = s >> 1, cb = (s & 1) * 32;
        const int ki = k / 3, kj = k - ki * 3;

        const float dy = params[(2 * k) * 65 + px];
        const float dx = params[(2 * k + 1) * 65 + px];
        const float mk = params[(18 + k) * 65 + px];

        const float ys = (float)(ho - 1 + ki) + dy;
        const float xs = (float)(wo - 1 + kj) + dx;
        const float y0f = floorf(ys), x0f = floorf(xs);
        const float wy = ys - y0f, wx = xs - x0f;
        const int y0 = (int)y0f, x0 = (int)x0f;
        const int y1 = y0 + 1,  x1 = x0 + 1;
        const bool vy0 = (y0 >= 0) && (y0 < H_);
        const bool vy1 = (y1 >= 0) && (y1 < H_);
        const bool vx0 = (x0 >= 0) && (x0 < W_);
        const bool vx1 = (x1 >= 0) && (x1 < W_);
        const int yc0 = min(max(y0, 0), H_ - 1);
        const int yc1 = min(max(y1, 0), H_ - 1);
        const int xc0 = min(max(x0, 0), W_ - 1);
        const int xc1 = min(max(x1, 0), W_ - 1);
        float w00 = (1.0f - wy) * (1.0f - wx) * mk; if (!(vy0 && vx0)) w00 = 0.0f;
        float w01 = (1.0f - wy) * wx          * mk; if (!(vy0 && vx1)) w01 = 0.0f;
        float w10 = wy          * (1.0f - wx) * mk; if (!(vy1 && vx0)) w10 = 0.0f;
        float w11 = wy          * wx          * mk; if (!(vy1 && vx1)) w11 = 0.0f;

        const int c0 = cb + h * 8;
        const float* __restrict__ p00 = xb + (size_t)c0 * HW_ + yc0 * W_ + xc0;
        const float* __restrict__ p01 = xb + (size_t)c0 * HW_ + yc0 * W_ + xc1;
        const float* __restrict__ p10 = xb + (size_t)c0 * HW_ + yc1 * W_ + xc0;
        const float* __restrict__ p11 = xb + (size_t)c0 * HW_ + yc1 * W_ + xc1;

        bf16x8 pv;
#pragma unroll
        for (int j = 0; j < 8; ++j) {
            const float val = fmaf(w00, p00[(size_t)j * HW_],
                             fmaf(w01, p01[(size_t)j * HW_],
                             fmaf(w10, p10[(size_t)j * HW_], w11 * p11[(size_t)j * HW_])));
            pv[j] = (__bf16)val;
        }
        bf16x8 af[4];
#pragma unroll
        for (int mt = 0; mt < 4; ++mt)
            af[mt] = *(const bf16x8*)&wpM[(size_t)((s * 4 + mt) * 64 + lane) * 8];

        __syncthreads();                     // prev step's Pl reads complete
        *(bf16x8*)&Pl[px * PSTR + h * 8] = pv;
        __syncthreads();
        const bf16x8 bf = *(const bf16x8*)&Pl[(wave * 16 + ln) * PSTR + lq * 8];
#pragma unroll
        for (int mt = 0; mt < 4; ++mt)
            acc[mt] = __builtin_amdgcn_mfma_f32_16x16x32_bf16(af[mt], bf, acc[mt], 0, 0, 0);
    }

    // Epilogue B: col = px (n-tile = wave), row = o.
    float* __restrict__ ob = out + (size_t)b * O_ * HW_ + (size_t)ho * W_ + xh * 64
                           + wave * 16 + ln;
#pragma unroll
    for (int mt = 0; mt < 4; ++mt)
#pragma unroll
        for (int r = 0; r < 4; ++r) {
            const int o = mt * 16 + lq * 4 + r;
            ob[(size_t)o * HW_] = acc[mt][r];
        }
}

extern "C" void kernel_launch(void* const* d_in, const int* in_sizes, int n_in,
                              void* d_out, int out_size, void* d_ws, size_t ws_size,
                              hipStream_t stream) {
    (void)in_sizes; (void)n_in; (void)out_size; (void)ws_size;
    const float* x    = (const float*)d_in[0];
    const float* offw = (const float*)d_in[1];
    const float* offb = (const float*)d_in[2];
    const float* modw = (const float*)d_in[3];
    const float* modb = (const float*)d_in[4];
    const float* wgt  = (const float*)d_in[5];
    float* out = (float*)d_out;

    __bf16* wpM = (__bf16*)d_ws;               // 73728 B
    __bf16* wpA = wpM + WPM_ELEMS;             // 36864 B (ws usage ~111 KB total)

    prepack_kernel<<<27, 256, 0, stream>>>(offw, modw, wgt, wpM, wpA);
    dcn_main_kernel<<<B_ * H_ * 2, 256, 0, stream>>>(x, wpA, wpM, offb, modb, out);
}

// Round 4
// 204.773 us; speedup vs baseline: 3.2172x; 1.4716x over previous
//
#include <hip/hip_runtime.h>
#include <math.h>

// Problem constants
#define B_   8
#define C_   64
#define O_   64
#define H_   128
#define W_   128
#define HW_  (H_ * W_)
#define KSZ  576            // C_*9 contraction length
#define PSTR 40             // Pl leading-dim stride (bf16); 80 B rows, 16B-aligned

typedef __bf16 bf16x8 __attribute__((ext_vector_type(8)));
typedef float  f32x4  __attribute__((ext_vector_type(4)));

#define WPM_BYTES (18 * 4 * 64 * 8 * 2)   // 73728
#define WPA_BYTES (18 * 2 * 64 * 8 * 2)   // 36864

// ---------------------------------------------------------------------------
// Prepack weights into bf16 MFMA A-fragment layout (same as round 3).
// ---------------------------------------------------------------------------
__global__ __launch_bounds__(256) void prepack_kernel(
    const float* __restrict__ offw, const float* __restrict__ modw,
    const float* __restrict__ wgt,
    __bf16* __restrict__ wpM, __bf16* __restrict__ wpA)
{
    const int g = blockIdx.x * 256 + threadIdx.x;
    if (g < 18 * 4 * 64) {
        const int s = g >> 8, mt = (g >> 6) & 3, lane = g & 63;
        const int k = s >> 1, cb = (s & 1) * 32;
        const int o  = mt * 16 + (lane & 15);
        const int c0 = cb + (lane >> 4) * 8;
        bf16x8 v;
#pragma unroll
        for (int j = 0; j < 8; ++j) v[j] = (__bf16)wgt[o * KSZ + (c0 + j) * 9 + k];
        *(bf16x8*)&wpM[(size_t)g * 8] = v;
    } else if (g < 18 * 4 * 64 + 18 * 2 * 64) {
        const int u = g - 18 * 4 * 64;
        const int s = u >> 7, mt = (u >> 6) & 1, lane = u & 63;
        const int k = s >> 1, cb = (s & 1) * 32;
        const int t  = mt * 16 + (lane & 15);
        const int c0 = cb + (lane >> 4) * 8;
        bf16x8 v;
#pragma unroll
        for (int j = 0; j < 8; ++j) {
            float w = 0.0f;
            if (t < 18)      w = offw[t * KSZ + (c0 + j) * 9 + k];
            else if (t < 27) w = modw[(t - 18) * KSZ + (c0 + j) * 9 + k];
            v[j] = (__bf16)w;
        }
        *(bf16x8*)&wpA[(size_t)u * 8] = v;
    }
}

// ---------------------------------------------------------------------------
// Transpose x: (B,C,H,W) fp32 -> (B,H,W,C) bf16. One thread per pixel.
// Reads coalesced (lanes = consecutive px at fixed c); writes 8x16B per thread.
// ---------------------------------------------------------------------------
__global__ __launch_bounds__(256) void xpose_kernel(
    const float* __restrict__ x, __bf16* __restrict__ xT)
{
    const int gpx = blockIdx.x * 256 + threadIdx.x;   // pixel in (B*H*W)
    const int b = gpx >> 14;                          // / HW_
    const int p = gpx & 16383;                        // % HW_
    const float* __restrict__ xp = x + (size_t)b * C_ * HW_ + p;
    __bf16* __restrict__ op = xT + (size_t)gpx * 64;
#pragma unroll
    for (int g = 0; g < 8; ++g) {
        bf16x8 v;
#pragma unroll
        for (int j = 0; j < 8; ++j)
            v[j] = (__bf16)xp[(size_t)(g * 8 + j) * HW_];
        *(bf16x8*)&op[g * 8] = v;
    }
}

// ---------------------------------------------------------------------------
// Fused main kernel. Block = 256 thr (4 waves) owns 64 px of one batch row.
// Phase A: im2col MFMA -> 27 params/px in LDS. Phase B: deformable gather
// (one 16B bf16x8 load per corner) -> LDS -> MFMA over 64 Cout.
// Pl double-buffered: ONE barrier per K-step.
// ---------------------------------------------------------------------------
__global__ __launch_bounds__(256) void dcn_main_kernel(
    const __bf16* __restrict__ xT,    // (B, H, W, C) bf16
    const __bf16* __restrict__ wpA,   // packed offset/mod weight frags
    const __bf16* __restrict__ wpM,   // packed main weight frags
    const float* __restrict__ offb,   // (18,)
    const float* __restrict__ modb,   // (9,)
    float* __restrict__ out)          // (B, O, H, W)
{
    __shared__ __align__(16) __bf16 Pl[2][64 * PSTR];  // double-buffered patches
    __shared__ float params[27 * 65];

    const int tid  = threadIdx.x;
    const int px   = tid & 63;           // local pixel
    const int h    = tid >> 6;           // 8-channel group (== wave id)
    const int lane = tid & 63;
    const int wave = tid >> 6;
    const int lq   = lane >> 4;
    const int ln   = lane & 15;

    const int bi   = blockIdx.x;
    const int b    = bi & 7;             // XCD-pinned batch
    const int rest = bi >> 3;
    const int ho   = rest >> 1;
    const int xh   = rest & 1;
    const int wo   = xh * 64 + px;

    const __bf16* __restrict__ xbT = xT + (size_t)b * HW_ * 64;

    // ---------------- Phase A: offset/modulator conv via MFMA ----------------
    f32x4 accA[2];
    accA[0] = (f32x4){0.f, 0.f, 0.f, 0.f};
    accA[1] = (f32x4){0.f, 0.f, 0.f, 0.f};

    for (int s = 0; s < 18; ++s) {
        const int k = s >> 1, cb = (s & 1) * 32;
        const int ki = k / 3, kj = k - ki * 3;
        const int y  = ho - 1 + ki;
        const int xx = wo - 1 + kj;
        const bool v = (y >= 0) && (y < H_) && (xx >= 0) && (xx < W_);
        bf16x8 pv;
        if (v) {
            pv = *(const bf16x8*)&xbT[((size_t)(y * W_ + xx)) * 64 + cb + h * 8];
        } else {
#pragma unroll
            for (int j = 0; j < 8; ++j) pv[j] = (__bf16)0.0f;
        }
        bf16x8 afA[2];
#pragma unroll
        for (int mt = 0; mt < 2; ++mt)
            afA[mt] = *(const bf16x8*)&wpA[(size_t)((s * 2 + mt) * 64 + lane) * 8];

        *(bf16x8*)&Pl[s & 1][px * PSTR + h * 8] = pv;
        __syncthreads();
        const bf16x8 bfA = *(const bf16x8*)&Pl[s & 1][(wave * 16 + ln) * PSTR + lq * 8];
#pragma unroll
        for (int mt = 0; mt < 2; ++mt)
            accA[mt] = __builtin_amdgcn_mfma_f32_16x16x32_bf16(afA[mt], bfA, accA[mt], 0, 0, 0);
    }
    __syncthreads();   // protect params/Pl transition

    // Epilogue A: col = lane&15 (px), row = quad*4 + r (param t).
#pragma unroll
    for (int mt = 0; mt < 2; ++mt)
#pragma unroll
        for (int r = 0; r < 4; ++r) {
            const int t   = mt * 16 + lq * 4 + r;
            const int pxl = wave * 16 + ln;
            const float val = accA[mt][r];
            if (t < 18)      params[t * 65 + pxl] = val + offb[t];
            else if (t < 27) params[t * 65 + pxl] = 2.0f / (1.0f + expf(-(val + modb[t - 18])));
        }
    __syncthreads();

    // ---------------- Phase B: deformable gather + MFMA ----------------
    f32x4 acc[4];
#pragma unroll
    for (int mt = 0; mt < 4; ++mt) acc[mt] = (f32x4){0.f, 0.f, 0.f, 0.f};

    for (int s = 0; s < 18; ++s) {
        const int k = s >> 1, cb = (s & 1) * 32;
        const int ki = k / 3, kj = k - ki * 3;

        const float dy = params[(2 * k) * 65 + px];
        const float dx = params[(2 * k + 1) * 65 + px];
        const float mk = params[(18 + k) * 65 + px];

        const float ys = (float)(ho - 1 + ki) + dy;
        const float xs = (float)(wo - 1 + kj) + dx;
        const float y0f = floorf(ys), x0f = floorf(xs);
        const float wy = ys - y0f, wx = xs - x0f;
        const int y0 = (int)y0f, x0 = (int)x0f;
        const int y1 = y0 + 1,  x1 = x0 + 1;
        const bool vy0 = (y0 >= 0) && (y0 < H_);
        const bool vy1 = (y1 >= 0) && (y1 < H_);
        const bool vx0 = (x0 >= 0) && (x0 < W_);
        const bool vx1 = (x1 >= 0) && (x1 < W_);
        const int yc0 = min(max(y0, 0), H_ - 1);
        const int yc1 = min(max(y1, 0), H_ - 1);
        const int xc0 = min(max(x0, 0), W_ - 1);
        const int xc1 = min(max(x1, 0), W_ - 1);
        float w00 = (1.0f - wy) * (1.0f - wx) * mk; if (!(vy0 && vx0)) w00 = 0.0f;
        float w01 = (1.0f - wy) * wx          * mk; if (!(vy0 && vx1)) w01 = 0.0f;
        float w10 = wy          * (1.0f - wx) * mk; if (!(vy1 && vx0)) w10 = 0.0f;
        float w11 = wy          * wx          * mk; if (!(vy1 && vx1)) w11 = 0.0f;

        const int c0 = cb + h * 8;
        const bf16x8 v00 = *(const bf16x8*)&xbT[((size_t)(yc0 * W_ + xc0)) * 64 + c0];
        const bf16x8 v01 = *(const bf16x8*)&xbT[((size_t)(yc0 * W_ + xc1)) * 64 + c0];
        const bf16x8 v10 = *(const bf16x8*)&xbT[((size_t)(yc1 * W_ + xc0)) * 64 + c0];
        const bf16x8 v11 = *(const bf16x8*)&xbT[((size_t)(yc1 * W_ + xc1)) * 64 + c0];

        bf16x8 pv;
#pragma unroll
        for (int j = 0; j < 8; ++j) {
            const float val = fmaf(w00, (float)v00[j],
                             fmaf(w01, (float)v01[j],
                             fmaf(w10, (float)v10[j], w11 * (float)v11[j])));
            pv[j] = (__bf16)val;
        }
        bf16x8 af[4];
#pragma unroll
        for (int mt = 0; mt < 4; ++mt)
            af[mt] = *(const bf16x8*)&wpM[(size_t)((s * 4 + mt) * 64 + lane) * 8];

        *(bf16x8*)&Pl[s & 1][px * PSTR + h * 8] = pv;
        __syncthreads();
        const bf16x8 bf = *(const bf16x8*)&Pl[s & 1][(wave * 16 + ln) * PSTR + lq * 8];
#pragma unroll
        for (int mt = 0; mt < 4; ++mt)
            acc[mt] = __builtin_amdgcn_mfma_f32_16x16x32_bf16(af[mt], bf, acc[mt], 0, 0, 0);
    }

    // Epilogue B: col = px (n-tile = wave), row = o.
    float* __restrict__ ob = out + (size_t)b * O_ * HW_ + (size_t)ho * W_ + xh * 64
                           + wave * 16 + ln;
#pragma unroll
    for (int mt = 0; mt < 4; ++mt)
#pragma unroll
        for (int r = 0; r < 4; ++r) {
            const int o = mt * 16 + lq * 4 + r;
            ob[(size_t)o * HW_] = acc[mt][r];
        }
}

extern "C" void kernel_launch(void* const* d_in, const int* in_sizes, int n_in,
                              void* d_out, int out_size, void* d_ws, size_t ws_size,
                              hipStream_t stream) {
    (void)in_sizes; (void)n_in; (void)out_size; (void)ws_size;
    const float* x    = (const float*)d_in[0];
    const float* offw = (const float*)d_in[1];
    const float* offb = (const float*)d_in[2];
    const float* modw = (const float*)d_in[3];
    const float* modb = (const float*)d_in[4];
    const float* wgt  = (const float*)d_in[5];
    float* out = (float*)d_out;

    __bf16* wpM = (__bf16*)d_ws;                               // 73728 B
    __bf16* wpA = (__bf16*)((char*)d_ws + WPM_BYTES);          // 36864 B
    __bf16* xT  = (__bf16*)((char*)d_ws + WPM_BYTES + WPA_BYTES);  // 16.78 MB

    prepack_kernel<<<27, 256, 0, stream>>>(offw, modw, wgt, wpM, wpA);
    xpose_kernel<<<(B_ * HW_) / 256, 256, 0, stream>>>(x, xT);
    dcn_main_kernel<<<B_ * H_ * 2, 256, 0, stream>>>(xT, wpA, wpM, offb, modb, out);
}

// Round 5
// 200.249 us; speedup vs baseline: 3.2899x; 1.0226x over previous
//
#include <hip/hip_runtime.h>
#include <math.h>

// Problem constants
#define B_   8
#define C_   64
#define O_   64
#define H_   128
#define W_   128
#define HW_  (H_ * W_)
#define KSZ  576            // C_*9 contraction length

typedef __bf16 bf16x8 __attribute__((ext_vector_type(8)));
typedef float  f32x4  __attribute__((ext_vector_type(4)));

#define WPM_BYTES (18 * 4 * 64 * 8 * 2)   // 73728
#define WPA_BYTES (18 * 2 * 64 * 8 * 2)   // 36864

// ---------------------------------------------------------------------------
// Prepack weights into bf16 MFMA A-fragment layout.
// Chunk s (0..17): tap k = s>>1, channel base cb = (s&1)*32.
// A-frag element (m-tile mt, lane, j): row = mt*16+(lane&15), kk = (lane>>4)*8+j.
// ---------------------------------------------------------------------------
__global__ __launch_bounds__(256) void prepack_kernel(
    const float* __restrict__ offw, const float* __restrict__ modw,
    const float* __restrict__ wgt,
    __bf16* __restrict__ wpM, __bf16* __restrict__ wpA)
{
    const int g = blockIdx.x * 256 + threadIdx.x;
    if (g < 18 * 4 * 64) {
        const int s = g >> 8, mt = (g >> 6) & 3, lane = g & 63;
        const int k = s >> 1, cb = (s & 1) * 32;
        const int o  = mt * 16 + (lane & 15);
        const int c0 = cb + (lane >> 4) * 8;
        bf16x8 v;
#pragma unroll
        for (int j = 0; j < 8; ++j) v[j] = (__bf16)wgt[o * KSZ + (c0 + j) * 9 + k];
        *(bf16x8*)&wpM[(size_t)g * 8] = v;
    } else if (g < 18 * 4 * 64 + 18 * 2 * 64) {
        const int u = g - 18 * 4 * 64;
        const int s = u >> 7, mt = (u >> 6) & 1, lane = u & 63;
        const int k = s >> 1, cb = (s & 1) * 32;
        const int t  = mt * 16 + (lane & 15);
        const int c0 = cb + (lane >> 4) * 8;
        bf16x8 v;
#pragma unroll
        for (int j = 0; j < 8; ++j) {
            float w = 0.0f;
            if (t < 18)      w = offw[t * KSZ + (c0 + j) * 9 + k];
            else if (t < 27) w = modw[(t - 18) * KSZ + (c0 + j) * 9 + k];
            v[j] = (__bf16)w;
        }
        *(bf16x8*)&wpA[(size_t)u * 8] = v;
    }
}

// ---------------------------------------------------------------------------
// Transpose x: (B,C,H,W) fp32 -> (B,H,W,C) bf16.
// One thread per (pixel, 8-channel group): 1M threads / 4096 blocks.
// Writes: lane-consecutive 16 B -> perfectly coalesced 1 KB/wave.
// ---------------------------------------------------------------------------
__global__ __launch_bounds__(256) void xpose_kernel(
    const float* __restrict__ x, __bf16* __restrict__ xT)
{
    const int t  = blockIdx.x * 256 + threadIdx.x;  // (pixel<<3) | cg
    const int p  = t >> 3;                          // global pixel (b*HW + pp)
    const int cg = t & 7;
    const int b  = p >> 14;
    const int pp = p & 16383;
    const float* __restrict__ xp = x + (size_t)b * C_ * HW_ + (size_t)(cg * 8) * HW_ + pp;
    bf16x8 v;
#pragma unroll
    for (int j = 0; j < 8; ++j) v[j] = (__bf16)xp[(size_t)j * HW_];
    *(bf16x8*)&xT[(size_t)t * 8] = v;
}

// ---------------------------------------------------------------------------
// Fused main kernel — BARRIER-FREE K-loops.
// Block = 256 thr = 4 independent waves; each wave owns 16 px of a row.
// Lane roles: ln = lane&15 -> pixel within wave tile; lq = lane>>4 -> 8-ch group.
// The bilinear gather result IS the MFMA B-fragment (n=ln, k=lq*8+j) — no LDS
// patch staging, no per-step __syncthreads. Params live in a per-wave LDS slab
// (same-wave produce/consume).
// ---------------------------------------------------------------------------
__global__ __launch_bounds__(256) void dcn_main_kernel(
    const __bf16* __restrict__ xT,    // (B, H, W, C) bf16
    const __bf16* __restrict__ wpA,   // packed offset/mod weight frags
    const __bf16* __restrict__ wpM,   // packed main weight frags
    const float* __restrict__ offb,   // (18,)
    const float* __restrict__ modb,   // (9,)
    float* __restrict__ out)          // (B, O, H, W)
{
    __shared__ float params[4][27][17];   // [wave][t][px-in-tile], pad 17

    const int tid  = threadIdx.x;
    const int lane = tid & 63;
    const int wave = tid >> 6;
    const int lq   = lane >> 4;          // quad -> channel group
    const int ln   = lane & 15;          // pixel within the wave's 16-px tile

    const int bi   = blockIdx.x;
    const int b    = bi & 7;             // XCD-pinned batch
    const int rest = bi >> 3;
    const int ho   = rest >> 1;
    const int xh   = rest & 1;
    const int wo   = xh * 64 + wave * 16 + ln;   // this lane's pixel column

    const __bf16* __restrict__ xbT = xT + (size_t)b * HW_ * 64;

    // ---------------- Phase A: offset/modulator conv via MFMA ----------------
    f32x4 accA[2];
    accA[0] = (f32x4){0.f, 0.f, 0.f, 0.f};
    accA[1] = (f32x4){0.f, 0.f, 0.f, 0.f};

#pragma unroll
    for (int s = 0; s < 18; ++s) {
        const int k = s >> 1, cb = (s & 1) * 32;
        const int ki = k / 3, kj = k - ki * 3;
        const int y  = ho - 1 + ki;
        const int xx = wo - 1 + kj;
        const bool v = (y >= 0) && (y < H_) && (xx >= 0) && (xx < W_);
        bf16x8 bfA;
        if (v) {
            bfA = *(const bf16x8*)&xbT[((size_t)(y * W_ + xx)) * 64 + cb + lq * 8];
        } else {
#pragma unroll
            for (int j = 0; j < 8; ++j) bfA[j] = (__bf16)0.0f;
        }
        bf16x8 afA[2];
#pragma unroll
        for (int mt = 0; mt < 2; ++mt)
            afA[mt] = *(const bf16x8*)&wpA[(size_t)((s * 2 + mt) * 64 + lane) * 8];
#pragma unroll
        for (int mt = 0; mt < 2; ++mt)
            accA[mt] = __builtin_amdgcn_mfma_f32_16x16x32_bf16(afA[mt], bfA, accA[mt], 0, 0, 0);
    }

    // Epilogue A: D col = ln (px-in-tile), row = lq*4 + r (+16*mt) = param t.
#pragma unroll
    for (int mt = 0; mt < 2; ++mt)
#pragma unroll
        for (int r = 0; r < 4; ++r) {
            const int t = mt * 16 + lq * 4 + r;
            const float val = accA[mt][r];
            if (t < 18)      params[wave][t][ln] = val + offb[t];
            else if (t < 27) params[wave][t][ln] = 2.0f / (1.0f + expf(-(val + modb[t - 18])));
        }
    __syncthreads();   // cheap; guarantees LDS visibility (also cross-wave safe)

    // ---------------- Phase B: deformable gather + MFMA (barrier-free) -------
    f32x4 acc[4];
#pragma unroll
    for (int mt = 0; mt < 4; ++mt) acc[mt] = (f32x4){0.f, 0.f, 0.f, 0.f};

#pragma unroll
    for (int s = 0; s < 18; ++s) {
        const int k = s >> 1, cb = (s & 1) * 32;
        const int ki = k / 3, kj = k - ki * 3;

        const float dy = params[wave][2 * k][ln];
        const float dx = params[wave][2 * k + 1][ln];
        const float mk = params[wave][18 + k][ln];

        const float ys = (float)(ho - 1 + ki) + dy;
        const float xs = (float)(wo - 1 + kj) + dx;
        const float y0f = floorf(ys), x0f = floorf(xs);
        const float wy = ys - y0f, wx = xs - x0f;
        const int y0 = (int)y0f, x0 = (int)x0f;
        const int y1 = y0 + 1,  x1 = x0 + 1;
        const bool vy0 = (y0 >= 0) && (y0 < H_);
        const bool vy1 = (y1 >= 0) && (y1 < H_);
        const bool vx0 = (x0 >= 0) && (x0 < W_);
        const bool vx1 = (x1 >= 0) && (x1 < W_);
        const int yc0 = min(max(y0, 0), H_ - 1);
        const int yc1 = min(max(y1, 0), H_ - 1);
        const int xc0 = min(max(x0, 0), W_ - 1);
        const int xc1 = min(max(x1, 0), W_ - 1);
        float w00 = (1.0f - wy) * (1.0f - wx) * mk; if (!(vy0 && vx0)) w00 = 0.0f;
        float w01 = (1.0f - wy) * wx          * mk; if (!(vy0 && vx1)) w01 = 0.0f;
        float w10 = wy          * (1.0f - wx) * mk; if (!(vy1 && vx0)) w10 = 0.0f;
        float w11 = wy          * wx          * mk; if (!(vy1 && vx1)) w11 = 0.0f;

        const int c0 = cb + lq * 8;
        const bf16x8 v00 = *(const bf16x8*)&xbT[((size_t)(yc0 * W_ + xc0)) * 64 + c0];
        const bf16x8 v01 = *(const bf16x8*)&xbT[((size_t)(yc0 * W_ + xc1)) * 64 + c0];
        const bf16x8 v10 = *(const bf16x8*)&xbT[((size_t)(yc1 * W_ + xc0)) * 64 + c0];
        const bf16x8 v11 = *(const bf16x8*)&xbT[((size_t)(yc1 * W_ + xc1)) * 64 + c0];

        bf16x8 bf;   // directly the MFMA B-fragment: n=ln, k=lq*8+j
#pragma unroll
        for (int j = 0; j < 8; ++j) {
            const float val = fmaf(w00, (float)v00[j],
                             fmaf(w01, (float)v01[j],
                             fmaf(w10, (float)v10[j], w11 * (float)v11[j])));
            bf[j] = (__bf16)val;
        }
        bf16x8 af[4];
#pragma unroll
        for (int mt = 0; mt < 4; ++mt)
            af[mt] = *(const bf16x8*)&wpM[(size_t)((s * 4 + mt) * 64 + lane) * 8];
#pragma unroll
        for (int mt = 0; mt < 4; ++mt)
            acc[mt] = __builtin_amdgcn_mfma_f32_16x16x32_bf16(af[mt], bf, acc[mt], 0, 0, 0);
    }

    // Epilogue B: D col = ln -> px = wo, row = o.
    float* __restrict__ ob = out + (size_t)b * O_ * HW_ + (size_t)ho * W_ + wo;
#pragma unroll
    for (int mt = 0; mt < 4; ++mt)
#pragma unroll
        for (int r = 0; r < 4; ++r) {
            const int o = mt * 16 + lq * 4 + r;
            ob[(size_t)o * HW_] = acc[mt][r];
        }
}

extern "C" void kernel_launch(void* const* d_in, const int* in_sizes, int n_in,
                              void* d_out, int out_size, void* d_ws, size_t ws_size,
                              hipStream_t stream) {
    (void)in_sizes; (void)n_in; (void)out_size; (void)ws_size;
    const float* x    = (const float*)d_in[0];
    const float* offw = (const float*)d_in[1];
    const float* offb = (const float*)d_in[2];
    const float* modw = (const float*)d_in[3];
    const float* modb = (const float*)d_in[4];
    const float* wgt  = (const float*)d_in[5];
    float* out = (float*)d_out;

    __bf16* wpM = (__bf16*)d_ws;                               // 73728 B
    __bf16* wpA = (__bf16*)((char*)d_ws + WPM_BYTES);          // 36864 B
    __bf16* xT  = (__bf16*)((char*)d_ws + WPM_BYTES + WPA_BYTES);  // 16.78 MB

    prepack_kernel<<<27, 256, 0, stream>>>(offw, modw, wgt, wpM, wpA);
    xpose_kernel<<<(B_ * HW_ * 8) / 256, 256, 0, stream>>>(x, xT);
    dcn_main_kernel<<<B_ * H_ * 2, 256, 0, stream>>>(xT, wpA, wpM, offb, modb, out);
}